// Round 1
// baseline (2786.280 us; speedup 1.0000x reference)
//
#include <hip/hip_runtime.h>
#include <hip/hip_bf16.h>

// ---------------------------------------------------------------------------
// 2-layer LSTM decoder, B=64, T=25, H=2048, IN=OUT=66, hardtanh feedback.
// Strategy: cast weights to bf16 once per launch, run per-step fused
// MFMA(16x16x32 bf16) LSTM-layer kernels + fp32 FC kernel. 77 launches total.
// ---------------------------------------------------------------------------

typedef short bfrag  __attribute__((ext_vector_type(8)));   // 8 bf16 (4 VGPR)
typedef float accv   __attribute__((ext_vector_type(4)));   // 4 fp32 acc
typedef float vfloat4 __attribute__((ext_vector_type(4)));
typedef unsigned short usvec4 __attribute__((ext_vector_type(4)));

#define LD8(p) (*(const bfrag*)(p))

__device__ __forceinline__ unsigned short f2bf(float x) {
    unsigned int u = __float_as_uint(x);
    unsigned int r = u + 0x7FFFu + ((u >> 16) & 1u);   // RTNE
    return (unsigned short)(r >> 16);
}

// --------------------------- weight cast (big) -----------------------------
// Whh0 / Wih1 / Whh1: each 8192x2048 fp32 -> bf16, contiguous dst.
__global__ void cast_big(const float* __restrict__ s0, const float* __restrict__ s1,
                         const float* __restrict__ s2, unsigned short* __restrict__ dst) {
    size_t t4 = ((size_t)blockIdx.x * 256 + threadIdx.x) * 4;
    int a = (int)(t4 >> 24);                 // 16777216 elements per array
    size_t r = t4 & 16777215u;
    const float* src = (a == 0) ? s0 : (a == 1) ? s1 : s2;
    vfloat4 v = *(const vfloat4*)(src + r);
    usvec4 u = { f2bf(v.x), f2bf(v.y), f2bf(v.z), f2bf(v.w) };
    *(usvec4*)(dst + t4) = u;
}

// --------------------------- state init ------------------------------------
// Ranges: Wih0 pad-cast [8192x66 -> 8192x96], h0/h1 bf16, c0/c1 fp32, x pad-cast.
__global__ void init_state(const float* __restrict__ inputs, const float* __restrict__ hiddens,
                           const float* __restrict__ cells,  const float* __restrict__ wih0,
                           unsigned short* __restrict__ wih0_bf,
                           unsigned short* __restrict__ h0bf, unsigned short* __restrict__ h1bf,
                           float* __restrict__ c0, float* __restrict__ c1,
                           unsigned short* __restrict__ xbf) {
    int i = blockIdx.x * 256 + threadIdx.x;
    if (i < 786432) {                        // 8192*96
        int r = i / 96, c = i - r * 96;
        wih0_bf[i] = (c < 66) ? f2bf(wih0[r * 66 + c]) : (unsigned short)0;
        return;
    }
    i -= 786432;
    if (i < 131072) { h0bf[i] = f2bf(hiddens[i]); return; }
    i -= 131072;
    if (i < 131072) { h1bf[i] = f2bf(hiddens[131072 + i]); return; }
    i -= 131072;
    if (i < 131072) { c0[i] = cells[i]; return; }
    i -= 131072;
    if (i < 131072) { c1[i] = cells[131072 + i]; return; }
    i -= 131072;
    if (i < 6144) {                          // 64*96 padded x
        int r = i / 96, c = i - r * 96;
        xbf[i] = (c < 66) ? f2bf(inputs[r * 66 + c]) : (unsigned short)0;
    }
}

// --------------------------- fused LSTM layer ------------------------------
// gates = A1 @ B1^T + A2 @ B2^T  (rows of B are gate rows, i|f|g|o blocks of 2048)
// block: j0 = blockIdx.x*8 hidden units, all 64 batches, all 4 gates.
// 8 waves: wave = (p<<2)|m ; m = batch tile (16), p selects gate-pair {0,1}/{2,3}.
// N-tile rows: lane n<8 -> gate (2p), unit j0+n ; n>=8 -> gate (2p+1), unit j0+n-8.

__device__ __forceinline__ void gemm_phase(const unsigned short* __restrict__ A,
                                           const unsigned short* __restrict__ Bm,
                                           int lda, int nc,
                                           int b_lane, int row, int koff, accv& acc) {
    const unsigned short* ap = A  + (size_t)b_lane * lda + koff;
    const unsigned short* bp = Bm + (size_t)row    * lda + koff;
    int ng = nc >> 2;
    if (ng > 0) {
        bfrag a0 = LD8(ap +  0), b0 = LD8(bp +  0);
        bfrag a1 = LD8(ap + 32), b1 = LD8(bp + 32);
        bfrag a2 = LD8(ap + 64), b2 = LD8(bp + 64);
        bfrag a3 = LD8(ap + 96), b3 = LD8(bp + 96);
        for (int g = 1; g < ng; ++g) {
            const unsigned short* ap2 = ap + (size_t)g * 128;
            const unsigned short* bp2 = bp + (size_t)g * 128;
            bfrag c0 = LD8(ap2 +  0), d0 = LD8(bp2 +  0);
            bfrag c1 = LD8(ap2 + 32), d1 = LD8(bp2 + 32);
            bfrag c2 = LD8(ap2 + 64), d2 = LD8(bp2 + 64);
            bfrag c3 = LD8(ap2 + 96), d3 = LD8(bp2 + 96);
            acc = __builtin_amdgcn_mfma_f32_16x16x32_bf16(a0, b0, acc, 0, 0, 0);
            acc = __builtin_amdgcn_mfma_f32_16x16x32_bf16(a1, b1, acc, 0, 0, 0);
            acc = __builtin_amdgcn_mfma_f32_16x16x32_bf16(a2, b2, acc, 0, 0, 0);
            acc = __builtin_amdgcn_mfma_f32_16x16x32_bf16(a3, b3, acc, 0, 0, 0);
            a0 = c0; b0 = d0; a1 = c1; b1 = d1; a2 = c2; b2 = d2; a3 = c3; b3 = d3;
        }
        acc = __builtin_amdgcn_mfma_f32_16x16x32_bf16(a0, b0, acc, 0, 0, 0);
        acc = __builtin_amdgcn_mfma_f32_16x16x32_bf16(a1, b1, acc, 0, 0, 0);
        acc = __builtin_amdgcn_mfma_f32_16x16x32_bf16(a2, b2, acc, 0, 0, 0);
        acc = __builtin_amdgcn_mfma_f32_16x16x32_bf16(a3, b3, acc, 0, 0, 0);
    }
    for (int t = ng << 2; t < nc; ++t) {
        bfrag av = LD8(ap + (size_t)t * 32);
        bfrag bv = LD8(bp + (size_t)t * 32);
        acc = __builtin_amdgcn_mfma_f32_16x16x32_bf16(av, bv, acc, 0, 0, 0);
    }
}

__global__ __launch_bounds__(512) void lstm_layer(
        const unsigned short* __restrict__ A1, int lda1, int nc1,
        const unsigned short* __restrict__ B1,
        const unsigned short* __restrict__ A2,   // [64][2048] bf16
        const unsigned short* __restrict__ B2,   // [8192][2048] bf16
        const float* __restrict__ bih, const float* __restrict__ bhh,
        float* __restrict__ c_state,             // [64][2048] fp32 in-place
        unsigned short* __restrict__ h_bf_out,   // [64][2048] bf16
        float* __restrict__ hT_out) {            // [2048][64] fp32 or nullptr
    __shared__ float gsm[64][33];                // [batch][gate*8+unit], +1 pad
    int tid  = threadIdx.x;
    int lane = tid & 63;
    int wave = tid >> 6;
    int m    = wave & 3;
    int p    = wave >> 2;
    int n    = lane & 15;
    int quad = lane >> 4;
    int koff = quad * 8;
    int j0   = blockIdx.x * 8;
    int b_lane = m * 16 + n;
    int row  = (p * 2 + (n >> 3)) * 2048 + j0 + (n & 7);

    accv acc = {0.f, 0.f, 0.f, 0.f};
    gemm_phase(A1, B1, lda1, nc1, b_lane, row, koff, acc);
    gemm_phase(A2, B2, 2048, 64,  b_lane, row, koff, acc);

    int colL = p * 16 + n;
    #pragma unroll
    for (int r = 0; r < 4; ++r)                  // C/D: row = quad*4 + r (batch)
        gsm[m * 16 + quad * 4 + r][colL] = acc[r];
    __syncthreads();

    // cell update: one thread per (batch, unit)
    int b  = tid >> 3;
    int jj = tid & 7;
    int j  = j0 + jj;
    float gi = gsm[b][jj]      + bih[j]          + bhh[j];
    float gf = gsm[b][8 + jj]  + bih[2048 + j]   + bhh[2048 + j];
    float gg = gsm[b][16 + jj] + bih[4096 + j]   + bhh[4096 + j];
    float go = gsm[b][24 + jj] + bih[6144 + j]   + bhh[6144 + j];
    float iv = 1.f / (1.f + __expf(-gi));
    float fv = 1.f / (1.f + __expf(-gf));
    float gv = tanhf(gg);
    float ov = 1.f / (1.f + __expf(-go));
    float cp = c_state[b * 2048 + j];
    float cn = fv * cp + iv * gv;
    float hn = ov * tanhf(cn);
    c_state[b * 2048 + j]  = cn;
    h_bf_out[b * 2048 + j] = f2bf(hn);
    if (hT_out) hT_out[(size_t)j * 64 + b] = hn;  // fp32 transposed for FC
}

// --------------------------- FC + hardtanh + feedback ----------------------
__global__ __launch_bounds__(512) void fc_kernel(
        const float* __restrict__ h1T,   // [2048][64]
        const float* __restrict__ fcw,   // [66][2048]
        const float* __restrict__ fcb,   // [66]
        float* __restrict__ out,         // [64][25][66]
        unsigned short* __restrict__ xbf,// [64][96]
        int t) {
    __shared__ float red[8][64];
    int o    = blockIdx.x;
    int lane = threadIdx.x & 63;         // batch
    int w    = threadIdx.x >> 6;         // k-chunk of 256
    const float* wr = fcw + (size_t)o * 2048 + w * 256;
    const float* hc = h1T + (size_t)(w * 256) * 64 + lane;
    float acc = 0.f;
    #pragma unroll 8
    for (int k = 0; k < 256; ++k)
        acc = fmaf(hc[(size_t)k * 64], wr[k], acc);
    red[w][lane] = acc;
    __syncthreads();
    if (threadIdx.x < 64) {
        float v = fcb[o];
        #pragma unroll
        for (int q = 0; q < 8; ++q) v += red[q][lane];
        v = fminf(1.f, fmaxf(-1.f, v));
        out[((size_t)lane * 25 + t) * 66 + o] = v;
        xbf[lane * 96 + o] = f2bf(v);
    }
}

// ---------------------------------------------------------------------------
extern "C" void kernel_launch(void* const* d_in, const int* in_sizes, int n_in,
                              void* d_out, int out_size, void* d_ws, size_t ws_size,
                              hipStream_t stream) {
    (void)in_sizes; (void)n_in; (void)out_size; (void)ws_size;
    const float* inputs  = (const float*)d_in[0];
    const float* hiddens = (const float*)d_in[1];
    const float* cells   = (const float*)d_in[2];
    const float* W_ih0   = (const float*)d_in[3];
    const float* W_hh0   = (const float*)d_in[4];
    const float* b_ih0   = (const float*)d_in[5];
    const float* b_hh0   = (const float*)d_in[6];
    const float* W_ih1   = (const float*)d_in[7];
    const float* W_hh1   = (const float*)d_in[8];
    const float* b_ih1   = (const float*)d_in[9];
    const float* b_hh1   = (const float*)d_in[10];
    const float* fc_w    = (const float*)d_in[11];
    const float* fc_b    = (const float*)d_in[12];
    float* out = (float*)d_out;

    // workspace layout (ushort elements unless noted); total ~104.9 MB
    unsigned short* whh0_bf = (unsigned short*)d_ws;       // 16777216
    unsigned short* wih1_bf = whh0_bf + 16777216;          // 16777216
    unsigned short* whh1_bf = wih1_bf + 16777216;          // 16777216
    unsigned short* wih0_bf = whh1_bf + 16777216;          // 786432 (8192x96 padded)
    unsigned short* h0bf0   = wih0_bf + 786432;            // 131072 each
    unsigned short* h0bf1   = h0bf0 + 131072;
    unsigned short* h1bf0   = h0bf1 + 131072;
    unsigned short* h1bf1   = h1bf0 + 131072;
    unsigned short* xbf     = h1bf1 + 131072;              // 6144 (64x96 padded)
    float* c0  = (float*)(xbf + 6144);                     // 131072 fp32 each
    float* c1  = c0 + 131072;
    float* h1T = c1 + 131072;                              // 2048x64 fp32

    cast_big<<<49152, 256, 0, stream>>>(W_hh0, W_ih1, W_hh1, whh0_bf);
    init_state<<<5144, 256, 0, stream>>>(inputs, hiddens, cells, W_ih0,
                                         wih0_bf, h0bf0, h1bf0, c0, c1, xbf);

    unsigned short* h0buf[2] = {h0bf0, h0bf1};
    unsigned short* h1buf[2] = {h1bf0, h1bf1};
    for (int t = 0; t < 25; ++t) {
        int cur = t & 1, nxt = cur ^ 1;
        lstm_layer<<<256, 512, 0, stream>>>(xbf, 96, 3, wih0_bf,
                                            h0buf[cur], whh0_bf,
                                            b_ih0, b_hh0, c0,
                                            h0buf[nxt], (float*)nullptr);
        lstm_layer<<<256, 512, 0, stream>>>(h0buf[nxt], 2048, 64, wih1_bf,
                                            h1buf[cur], whh1_bf,
                                            b_ih1, b_hh1, c1,
                                            h1buf[nxt], h1T);
        fc_kernel<<<66, 512, 0, stream>>>(h1T, fc_w, fc_b, out, xbf, t);
    }
}